// Round 3
// baseline (147.463 us; speedup 1.0000x reference)
//
#include <hip/hip_runtime.h>

// Bahdanau additive attention, S=T=512, DU=DT=512, D=1024, fp32.
// score[t,s] = b_s + sum_d w[d]*tanh(A[s,d]+B[t,d]);  out = softmax_s(score) @ rnn
// tanh(x) = 1 - 2/(exp(2x)+1)  ->  score = const - 2*sum_d w*rcp(exp2(C2*(a+b))+1)
// const drops under softmax; C2=2*log2(e) folded into A,B at k1 epilogue.
// ws (floats): A[512K] | B[512K] | P[nz][256K] | wgt[256K]; k4 partials alias P.

#define C2F 2.8853900817779268f   // 2*log2(e)

// ---- k1: A = (rnn @ W[:, :512].T) * C2 ; B = (tgt @ W[:, 512:].T + b_lin) * C2 ----
__global__ __launch_bounds__(256, 4) void k1_gemm_ab(
    const float* __restrict__ rnn, const float* __restrict__ tgt,
    const float* __restrict__ W, const float* __restrict__ bl,
    float* __restrict__ A, float* __restrict__ B)
{
    __shared__ float xt[64][34];   // [k][i]
    __shared__ float wt[64][34];   // [k][j]
    const int j0 = blockIdx.x * 32;
    const int i0 = blockIdx.y * 32;
    const bool isB = (i0 >= 512);
    const float* __restrict__ in = isB ? tgt : rnn;
    const int irow0 = isB ? (i0 - 512) : i0;
    const int koff = isB ? 512 : 0;
    const int tid = threadIdx.x;
    const int lrow = tid >> 3;
    const int q    = tid & 7;
    const int ii   = (tid & 15) * 2;
    const int jj   = (tid >> 4) * 2;
    float a00 = 0.f, a01 = 0.f, a10 = 0.f, a11 = 0.f;
    for (int k0 = 0; k0 < 512; k0 += 64) {
        const float4 x0 = *(const float4*)(in + (size_t)(irow0 + lrow) * 512 + k0 + q * 8);
        const float4 x1 = *(const float4*)(in + (size_t)(irow0 + lrow) * 512 + k0 + q * 8 + 4);
        const float4 w0 = *(const float4*)(W + (size_t)(j0 + lrow) * 1024 + koff + k0 + q * 8);
        const float4 w1 = *(const float4*)(W + (size_t)(j0 + lrow) * 1024 + koff + k0 + q * 8 + 4);
        __syncthreads();
        xt[q*8+0][lrow] = x0.x; xt[q*8+1][lrow] = x0.y; xt[q*8+2][lrow] = x0.z; xt[q*8+3][lrow] = x0.w;
        xt[q*8+4][lrow] = x1.x; xt[q*8+5][lrow] = x1.y; xt[q*8+6][lrow] = x1.z; xt[q*8+7][lrow] = x1.w;
        wt[q*8+0][lrow] = w0.x; wt[q*8+1][lrow] = w0.y; wt[q*8+2][lrow] = w0.z; wt[q*8+3][lrow] = w0.w;
        wt[q*8+4][lrow] = w1.x; wt[q*8+5][lrow] = w1.y; wt[q*8+6][lrow] = w1.z; wt[q*8+7][lrow] = w1.w;
        __syncthreads();
        #pragma unroll
        for (int k = 0; k < 64; ++k) {
            const float2 av = *(const float2*)&xt[k][ii];
            const float2 bv = *(const float2*)&wt[k][jj];
            a00 = __builtin_fmaf(av.x, bv.x, a00);
            a01 = __builtin_fmaf(av.x, bv.y, a01);
            a10 = __builtin_fmaf(av.y, bv.x, a10);
            a11 = __builtin_fmaf(av.y, bv.y, a11);
        }
    }
    float b0 = 0.f, b1 = 0.f;
    if (isB) { b0 = bl[j0 + jj]; b1 = bl[j0 + jj + 1]; }
    float* __restrict__ dst = isB ? B : A;
    float2 o0, o1;
    o0.x = (a00 + b0) * C2F; o0.y = (a01 + b1) * C2F;
    o1.x = (a10 + b0) * C2F; o1.y = (a11 + b1) * C2F;
    *(float2*)(dst + (size_t)(irow0 + ii) * 1024 + j0 + jj)     = o0;
    *(float2*)(dst + (size_t)(irow0 + ii + 1) * 1024 + j0 + jj) = o1;
}

// ---- k2 (hot): P[z][t][s] = sum_{d in chunk z} w[d] * rcp(exp2(a+b)+1) ----
// 32x32 (t,s) tile, 2x2 micro, d split nz ways; register-prefetch next chunk.
__global__ __launch_bounds__(256, 8) void k2_scores(
    const float* __restrict__ A, const float* __restrict__ Bm,
    const float* __restrict__ wsc, float* __restrict__ P, int dchunk)
{
    __shared__ float at[32][34];   // [d][s]
    __shared__ float bt[32][34];   // [d][t]
    __shared__ float wl[256];
    const int s0 = blockIdx.x * 32;
    const int t0 = blockIdx.y * 32;
    const int dz = blockIdx.z * dchunk;
    const int tid = threadIdx.x;
    if (tid < dchunk) wl[tid] = wsc[dz + tid];
    const int lrow = tid >> 3;
    const int q    = tid & 7;
    const int ss   = (tid & 15) * 2;
    const int tt   = (tid >> 4) * 2;
    const float* __restrict__ Arow = A  + (size_t)(s0 + lrow) * 1024 + dz + q * 4;
    const float* __restrict__ Brow = Bm + (size_t)(t0 + lrow) * 1024 + dz + q * 4;
    float acc00 = 0.f, acc01 = 0.f, acc10 = 0.f, acc11 = 0.f;
    float4 av = *(const float4*)(Arow);
    float4 bv = *(const float4*)(Brow);
    for (int d0 = 0; d0 < dchunk; d0 += 32) {
        __syncthreads();
        at[q*4+0][lrow] = av.x; at[q*4+1][lrow] = av.y;
        at[q*4+2][lrow] = av.z; at[q*4+3][lrow] = av.w;
        bt[q*4+0][lrow] = bv.x; bt[q*4+1][lrow] = bv.y;
        bt[q*4+2][lrow] = bv.z; bt[q*4+3][lrow] = bv.w;
        __syncthreads();
        if (d0 + 32 < dchunk) {             // prefetch next chunk under compute
            av = *(const float4*)(Arow + d0 + 32);
            bv = *(const float4*)(Brow + d0 + 32);
        }
        #pragma unroll
        for (int d = 0; d < 32; ++d) {
            const float w = wl[d0 + d];
            const float2 a = *(const float2*)&at[d][ss];
            const float2 b = *(const float2*)&bt[d][tt];
            float x, r;
            x = a.x + b.x;
            r = __builtin_amdgcn_rcpf(__builtin_amdgcn_exp2f(x) + 1.f);
            acc00 = __builtin_fmaf(w, r, acc00);
            x = a.y + b.x;
            r = __builtin_amdgcn_rcpf(__builtin_amdgcn_exp2f(x) + 1.f);
            acc01 = __builtin_fmaf(w, r, acc01);
            x = a.x + b.y;
            r = __builtin_amdgcn_rcpf(__builtin_amdgcn_exp2f(x) + 1.f);
            acc10 = __builtin_fmaf(w, r, acc10);
            x = a.y + b.y;
            r = __builtin_amdgcn_rcpf(__builtin_amdgcn_exp2f(x) + 1.f);
            acc11 = __builtin_fmaf(w, r, acc11);
        }
    }
    float* __restrict__ Pz = P + (size_t)blockIdx.z * 512 * 512;
    float2 o0, o1;
    o0.x = acc00; o0.y = acc01;
    o1.x = acc10; o1.y = acc11;
    *(float2*)(Pz + (size_t)(t0 + tt) * 512 + s0 + ss)     = o0;
    *(float2*)(Pz + (size_t)(t0 + tt + 1) * 512 + s0 + ss) = o1;
}

// ---- k3: weights[t][:] = softmax_s( -2 * sum_z P_z[t][:] ) ----
__global__ __launch_bounds__(256, 4) void k3_softmax(
    const float* __restrict__ P, float* __restrict__ wgt, int nz)
{
    __shared__ float wm[4];
    __shared__ float wsum[4];
    const int t = blockIdx.x;
    const int tid = threadIdx.x;
    const size_t base = (size_t)t * 512 + tid * 2;
    float sx = 0.f, sy = 0.f;
    for (int z = 0; z < nz; ++z) {
        const float2 p = *(const float2*)(P + base + (size_t)z * 262144);
        sx += p.x; sy += p.y;
    }
    const float x0 = -2.f * sx;
    const float x1 = -2.f * sy;
    float m = fmaxf(x0, x1);
    #pragma unroll
    for (int off = 32; off; off >>= 1) m = fmaxf(m, __shfl_xor(m, off));
    if ((tid & 63) == 0) wm[tid >> 6] = m;
    __syncthreads();
    m = fmaxf(fmaxf(wm[0], wm[1]), fmaxf(wm[2], wm[3]));
    const float L2E = 1.4426950408889634f;
    const float e0 = __builtin_amdgcn_exp2f((x0 - m) * L2E);
    const float e1 = __builtin_amdgcn_exp2f((x1 - m) * L2E);
    float s = e0 + e1;
    #pragma unroll
    for (int off = 32; off; off >>= 1) s += __shfl_xor(s, off);
    if ((tid & 63) == 0) wsum[tid >> 6] = s;
    __syncthreads();
    s = wsum[0] + wsum[1] + wsum[2] + wsum[3];
    const float inv = 1.0f / s;
    float2 o; o.x = e0 * inv; o.y = e1 * inv;
    *(float2*)(wgt + (size_t)t * 512 + tid * 2) = o;
}

// ---- k4: P4[z] = wgt[:, z*128:(z+1)*128] @ rnn[z*128:(z+1)*128, :] ----
__global__ __launch_bounds__(256, 4) void k4_out(
    const float* __restrict__ wgt, const float* __restrict__ rnn,
    float* __restrict__ P4)
{
    __shared__ float wt_t[32][36];  // [s][t]
    __shared__ float rn[32][36];    // [s][d]
    const int t0 = blockIdx.y * 32;
    const int d0 = blockIdx.x * 32;
    const int z  = blockIdx.z;
    const int tid = threadIdx.x;
    const int lrow = tid >> 3;
    const int q    = tid & 7;
    const int tt   = (tid >> 4) * 2;
    const int dd   = (tid & 15) * 2;
    float a00 = 0.f, a01 = 0.f, a10 = 0.f, a11 = 0.f;
    for (int s0 = z * 128; s0 < z * 128 + 128; s0 += 32) {
        const float4 wv = *(const float4*)(wgt + (size_t)(t0 + lrow) * 512 + s0 + q * 4);
        const float4 rv = *(const float4*)(rnn + (size_t)(s0 + lrow) * 512 + d0 + q * 4);
        __syncthreads();
        wt_t[q*4+0][lrow] = wv.x; wt_t[q*4+1][lrow] = wv.y;
        wt_t[q*4+2][lrow] = wv.z; wt_t[q*4+3][lrow] = wv.w;
        rn[lrow][q*4+0] = rv.x; rn[lrow][q*4+1] = rv.y;
        rn[lrow][q*4+2] = rv.z; rn[lrow][q*4+3] = rv.w;
        __syncthreads();
        #pragma unroll
        for (int s = 0; s < 32; ++s) {
            const float w0 = wt_t[s][tt], w1 = wt_t[s][tt + 1];
            const float r0 = rn[s][dd],   r1 = rn[s][dd + 1];
            a00 = __builtin_fmaf(w0, r0, a00);
            a01 = __builtin_fmaf(w0, r1, a01);
            a10 = __builtin_fmaf(w1, r0, a10);
            a11 = __builtin_fmaf(w1, r1, a11);
        }
    }
    float* __restrict__ Pz = P4 + (size_t)z * 262144;
    Pz[(size_t)(t0 + tt) * 512 + d0 + dd]           = a00;
    Pz[(size_t)(t0 + tt) * 512 + d0 + dd + 1]       = a01;
    Pz[(size_t)(t0 + tt + 1) * 512 + d0 + dd]       = a10;
    Pz[(size_t)(t0 + tt + 1) * 512 + d0 + dd + 1]   = a11;
}

// ---- k5: out = P4[0]+P4[1]+P4[2]+P4[3] ----
__global__ __launch_bounds__(256, 4) void k5_reduce(
    const float* __restrict__ P4, float* __restrict__ out)
{
    const int i = (blockIdx.x * 256 + threadIdx.x) * 4;
    float4 a = *(const float4*)(P4 + i);
    const float4 b = *(const float4*)(P4 + 262144 + i);
    const float4 c = *(const float4*)(P4 + 2 * 262144 + i);
    const float4 d = *(const float4*)(P4 + 3 * 262144 + i);
    a.x += b.x + c.x + d.x;
    a.y += b.y + c.y + d.y;
    a.z += b.z + c.z + d.z;
    a.w += b.w + c.w + d.w;
    *(float4*)(out + i) = a;
}

extern "C" void kernel_launch(void* const* d_in, const int* in_sizes, int n_in,
                              void* d_out, int out_size, void* d_ws, size_t ws_size,
                              hipStream_t stream) {
    const float* rnn = (const float*)d_in[0];
    const float* tgt = (const float*)d_in[1];
    const float* W   = (const float*)d_in[2];
    const float* bl  = (const float*)d_in[3];
    const float* wsc = (const float*)d_in[4];
    // d_in[5] (b_score): constant shift under softmax -> unused.
    float* out = (float*)d_out;

    // nz=8 needs (2*524288 + 8*262144 + 262144)*4 = 13,631,488 B of ws.
    const int nz = (ws_size >= 13631488u) ? 8 : 4;
    const int dchunk = 1024 / nz;

    float* A   = (float*)d_ws;                  // 512*1024
    float* B   = A + 524288;                    // 512*1024
    float* P   = B + 524288;                    // nz * 262144
    float* wgt = P + (size_t)nz * 262144;       // 262144
    float* P4  = P;                             // alias: P dead after k3 (4*262144 <= nz*262144)

    k1_gemm_ab<<<dim3(32, 32),     256, 0, stream>>>(rnn, tgt, W, bl, A, B);
    k2_scores <<<dim3(16, 16, nz), 256, 0, stream>>>(A, B, wsc, P, dchunk);
    k3_softmax<<<512,              256, 0, stream>>>(P, wgt, nz);
    k4_out    <<<dim3(16, 16, 4),  256, 0, stream>>>(wgt, rnn, P4);
    k5_reduce <<<256,              256, 0, stream>>>(P4, out);
}

// Round 4
// 102.383 us; speedup vs baseline: 1.4403x; 1.4403x over previous
//
#include <hip/hip_runtime.h>

// Bahdanau additive attention, S=T=512, DU=DT=512, D=1024, fp32.
// score[t,s] = b_s + sum_d w[d]*tanh(A[s,d]+B[t,d]);  out = softmax_s(score) @ rnn
// tanh(x) = 1 - 2/(exp(2x)+1)  ->  score = const - 2*sum_d w*rcp(exp2(C2*(a+b))+1)
// const drops under softmax; C2=2*log2(e) folded into A,B at k1 epilogue.
// ws (floats): A[512K] | B[512K] | P[8][256K] | wgt[256K]; k4 partials alias P.

#define C2F 2.8853900817779268f   // 2*log2(e)

// ---- k1: A = (rnn @ W[:, :512].T) * C2 ; B = (tgt @ W[:, 512:].T + b_lin) * C2 ----
// 64x64 tile, 4x4 micro, k-chunk 32, register prefetch. 256 blocks.
__global__ __launch_bounds__(256) void k1_gemm_ab(
    const float* __restrict__ rnn, const float* __restrict__ tgt,
    const float* __restrict__ W, const float* __restrict__ bl,
    float* __restrict__ A, float* __restrict__ B)
{
    __shared__ float xt[32][66];   // [k][i]  (stride 66: 2-way bank alias only)
    __shared__ float wt[32][66];   // [k][j]
    const int j0 = blockIdx.x * 64;
    const int i0 = blockIdx.y * 64;
    const bool isB = (i0 >= 512);
    const float* __restrict__ in = isB ? tgt : rnn;
    const int irow0 = isB ? (i0 - 512) : i0;
    const int koff = isB ? 512 : 0;
    const int tid = threadIdx.x;
    const int lrow = tid >> 2;     // 0..63
    const int kq   = tid & 3;      // k offset = kq*8
    const int ti   = tid >> 4;     // 0..15 -> i micro row base ti*4
    const int tj   = tid & 15;     // 0..15 -> j micro col base tj*4
    const float* __restrict__ inp = in + (size_t)(irow0 + lrow) * 512 + kq * 8;
    const float* __restrict__ wp  = W  + (size_t)(j0 + lrow) * 1024 + koff + kq * 8;
    float acc[4][4] = {};
    float4 x0 = *(const float4*)(inp);
    float4 x1 = *(const float4*)(inp + 4);
    float4 w0 = *(const float4*)(wp);
    float4 w1 = *(const float4*)(wp + 4);
    for (int k0 = 0; k0 < 512; k0 += 32) {
        __syncthreads();
        xt[kq*8+0][lrow] = x0.x; xt[kq*8+1][lrow] = x0.y; xt[kq*8+2][lrow] = x0.z; xt[kq*8+3][lrow] = x0.w;
        xt[kq*8+4][lrow] = x1.x; xt[kq*8+5][lrow] = x1.y; xt[kq*8+6][lrow] = x1.z; xt[kq*8+7][lrow] = x1.w;
        wt[kq*8+0][lrow] = w0.x; wt[kq*8+1][lrow] = w0.y; wt[kq*8+2][lrow] = w0.z; wt[kq*8+3][lrow] = w0.w;
        wt[kq*8+4][lrow] = w1.x; wt[kq*8+5][lrow] = w1.y; wt[kq*8+6][lrow] = w1.z; wt[kq*8+7][lrow] = w1.w;
        __syncthreads();
        if (k0 + 32 < 512) {       // prefetch next chunk under compute
            x0 = *(const float4*)(inp + k0 + 32);
            x1 = *(const float4*)(inp + k0 + 36);
            w0 = *(const float4*)(wp + k0 + 32);
            w1 = *(const float4*)(wp + k0 + 36);
        }
        #pragma unroll
        for (int k = 0; k < 32; ++k) {
            const float2 a0 = *(const float2*)&xt[k][ti * 4];
            const float2 a1 = *(const float2*)&xt[k][ti * 4 + 2];
            const float2 b0 = *(const float2*)&wt[k][tj * 4];
            const float2 b1 = *(const float2*)&wt[k][tj * 4 + 2];
            const float ar[4] = {a0.x, a0.y, a1.x, a1.y};
            const float br[4] = {b0.x, b0.y, b1.x, b1.y};
            #pragma unroll
            for (int r = 0; r < 4; ++r)
                #pragma unroll
                for (int c = 0; c < 4; ++c)
                    acc[r][c] = __builtin_fmaf(ar[r], br[c], acc[r][c]);
        }
    }
    float4 bq = make_float4(0.f, 0.f, 0.f, 0.f);
    if (isB) bq = *(const float4*)(bl + j0 + tj * 4);
    float* __restrict__ dst = isB ? B : A;
    #pragma unroll
    for (int r = 0; r < 4; ++r) {
        float4 o;
        o.x = (acc[r][0] + bq.x) * C2F;
        o.y = (acc[r][1] + bq.y) * C2F;
        o.z = (acc[r][2] + bq.z) * C2F;
        o.w = (acc[r][3] + bq.w) * C2F;
        *(float4*)(dst + (size_t)(irow0 + ti * 4 + r) * 1024 + j0 + tj * 4) = o;
    }
}

// ---- k2 (hot): P[z][t][s] = sum_{d in chunk z} w[d] * rcp(exp2(a+b)+1) ----
// 32x32 (t,s) tile, 2x2 micro, d split 8 ways; register-prefetch next chunk.
__global__ __launch_bounds__(256, 4) void k2_scores(
    const float* __restrict__ A, const float* __restrict__ Bm,
    const float* __restrict__ wsc, float* __restrict__ P, int dchunk)
{
    __shared__ float at[32][34];   // [d][s]
    __shared__ float bt[32][34];   // [d][t]
    __shared__ float wl[256];
    const int s0 = blockIdx.x * 32;
    const int t0 = blockIdx.y * 32;
    const int dz = blockIdx.z * dchunk;
    const int tid = threadIdx.x;
    if (tid < dchunk) wl[tid] = wsc[dz + tid];
    const int lrow = tid >> 3;
    const int q    = tid & 7;
    const int ss   = (tid & 15) * 2;
    const int tt   = (tid >> 4) * 2;
    const float* __restrict__ Arow = A  + (size_t)(s0 + lrow) * 1024 + dz + q * 4;
    const float* __restrict__ Brow = Bm + (size_t)(t0 + lrow) * 1024 + dz + q * 4;
    float acc00 = 0.f, acc01 = 0.f, acc10 = 0.f, acc11 = 0.f;
    float4 av = *(const float4*)(Arow);
    float4 bv = *(const float4*)(Brow);
    for (int d0 = 0; d0 < dchunk; d0 += 32) {
        __syncthreads();
        at[q*4+0][lrow] = av.x; at[q*4+1][lrow] = av.y;
        at[q*4+2][lrow] = av.z; at[q*4+3][lrow] = av.w;
        bt[q*4+0][lrow] = bv.x; bt[q*4+1][lrow] = bv.y;
        bt[q*4+2][lrow] = bv.z; bt[q*4+3][lrow] = bv.w;
        __syncthreads();
        if (d0 + 32 < dchunk) {             // prefetch next chunk under compute
            av = *(const float4*)(Arow + d0 + 32);
            bv = *(const float4*)(Brow + d0 + 32);
        }
        #pragma unroll
        for (int d = 0; d < 32; ++d) {
            const float w = wl[d0 + d];
            const float2 a = *(const float2*)&at[d][ss];
            const float2 b = *(const float2*)&bt[d][tt];
            float x, r;
            x = a.x + b.x;
            r = __builtin_amdgcn_rcpf(__builtin_amdgcn_exp2f(x) + 1.f);
            acc00 = __builtin_fmaf(w, r, acc00);
            x = a.y + b.x;
            r = __builtin_amdgcn_rcpf(__builtin_amdgcn_exp2f(x) + 1.f);
            acc01 = __builtin_fmaf(w, r, acc01);
            x = a.x + b.y;
            r = __builtin_amdgcn_rcpf(__builtin_amdgcn_exp2f(x) + 1.f);
            acc10 = __builtin_fmaf(w, r, acc10);
            x = a.y + b.y;
            r = __builtin_amdgcn_rcpf(__builtin_amdgcn_exp2f(x) + 1.f);
            acc11 = __builtin_fmaf(w, r, acc11);
        }
    }
    float* __restrict__ Pz = P + (size_t)blockIdx.z * 512 * 512;
    float2 o0, o1;
    o0.x = acc00; o0.y = acc01;
    o1.x = acc10; o1.y = acc11;
    *(float2*)(Pz + (size_t)(t0 + tt) * 512 + s0 + ss)     = o0;
    *(float2*)(Pz + (size_t)(t0 + tt + 1) * 512 + s0 + ss) = o1;
}

// ---- k3: weights[t][:] = softmax_s( -2 * sum_z P_z[t][:] ) ----
__global__ __launch_bounds__(256, 4) void k3_softmax(
    const float* __restrict__ P, float* __restrict__ wgt, int nz)
{
    __shared__ float wm[4];
    __shared__ float wsum[4];
    const int t = blockIdx.x;
    const int tid = threadIdx.x;
    const size_t base = (size_t)t * 512 + tid * 2;
    float sx = 0.f, sy = 0.f;
    for (int z = 0; z < nz; ++z) {
        const float2 p = *(const float2*)(P + base + (size_t)z * 262144);
        sx += p.x; sy += p.y;
    }
    const float x0 = -2.f * sx;
    const float x1 = -2.f * sy;
    float m = fmaxf(x0, x1);
    #pragma unroll
    for (int off = 32; off; off >>= 1) m = fmaxf(m, __shfl_xor(m, off));
    if ((tid & 63) == 0) wm[tid >> 6] = m;
    __syncthreads();
    m = fmaxf(fmaxf(wm[0], wm[1]), fmaxf(wm[2], wm[3]));
    const float L2E = 1.4426950408889634f;
    const float e0 = __builtin_amdgcn_exp2f((x0 - m) * L2E);
    const float e1 = __builtin_amdgcn_exp2f((x1 - m) * L2E);
    float s = e0 + e1;
    #pragma unroll
    for (int off = 32; off; off >>= 1) s += __shfl_xor(s, off);
    if ((tid & 63) == 0) wsum[tid >> 6] = s;
    __syncthreads();
    s = wsum[0] + wsum[1] + wsum[2] + wsum[3];
    const float inv = 1.0f / s;
    float2 o; o.x = e0 * inv; o.y = e1 * inv;
    *(float2*)(wgt + (size_t)t * 512 + tid * 2) = o;
}

// ---- k4: P4[z] = wgt[:, z*128:(z+1)*128] @ rnn[z*128:(z+1)*128, :] ----
__global__ __launch_bounds__(256, 4) void k4_out(
    const float* __restrict__ wgt, const float* __restrict__ rnn,
    float* __restrict__ P4)
{
    __shared__ float wt_t[32][36];  // [s][t]
    __shared__ float rn[32][36];    // [s][d]
    const int t0 = blockIdx.y * 32;
    const int d0 = blockIdx.x * 32;
    const int z  = blockIdx.z;
    const int tid = threadIdx.x;
    const int lrow = tid >> 3;
    const int q    = tid & 7;
    const int tt   = (tid >> 4) * 2;
    const int dd   = (tid & 15) * 2;
    float a00 = 0.f, a01 = 0.f, a10 = 0.f, a11 = 0.f;
    for (int s0 = z * 128; s0 < z * 128 + 128; s0 += 32) {
        const float4 wv = *(const float4*)(wgt + (size_t)(t0 + lrow) * 512 + s0 + q * 4);
        const float4 rv = *(const float4*)(rnn + (size_t)(s0 + lrow) * 512 + d0 + q * 4);
        __syncthreads();
        wt_t[q*4+0][lrow] = wv.x; wt_t[q*4+1][lrow] = wv.y;
        wt_t[q*4+2][lrow] = wv.z; wt_t[q*4+3][lrow] = wv.w;
        rn[lrow][q*4+0] = rv.x; rn[lrow][q*4+1] = rv.y;
        rn[lrow][q*4+2] = rv.z; rn[lrow][q*4+3] = rv.w;
        __syncthreads();
        #pragma unroll
        for (int s = 0; s < 32; ++s) {
            const float w0 = wt_t[s][tt], w1 = wt_t[s][tt + 1];
            const float r0 = rn[s][dd],   r1 = rn[s][dd + 1];
            a00 = __builtin_fmaf(w0, r0, a00);
            a01 = __builtin_fmaf(w0, r1, a01);
            a10 = __builtin_fmaf(w1, r0, a10);
            a11 = __builtin_fmaf(w1, r1, a11);
        }
    }
    float* __restrict__ Pz = P4 + (size_t)z * 262144;
    Pz[(size_t)(t0 + tt) * 512 + d0 + dd]           = a00;
    Pz[(size_t)(t0 + tt) * 512 + d0 + dd + 1]       = a01;
    Pz[(size_t)(t0 + tt + 1) * 512 + d0 + dd]       = a10;
    Pz[(size_t)(t0 + tt + 1) * 512 + d0 + dd + 1]   = a11;
}

// ---- k5: out = P4[0]+P4[1]+P4[2]+P4[3] ----
__global__ __launch_bounds__(256, 4) void k5_reduce(
    const float* __restrict__ P4, float* __restrict__ out)
{
    const int i = (blockIdx.x * 256 + threadIdx.x) * 4;
    float4 a = *(const float4*)(P4 + i);
    const float4 b = *(const float4*)(P4 + 262144 + i);
    const float4 c = *(const float4*)(P4 + 2 * 262144 + i);
    const float4 d = *(const float4*)(P4 + 3 * 262144 + i);
    a.x += b.x + c.x + d.x;
    a.y += b.y + c.y + d.y;
    a.z += b.z + c.z + d.z;
    a.w += b.w + c.w + d.w;
    *(float4*)(out + i) = a;
}

extern "C" void kernel_launch(void* const* d_in, const int* in_sizes, int n_in,
                              void* d_out, int out_size, void* d_ws, size_t ws_size,
                              hipStream_t stream) {
    const float* rnn = (const float*)d_in[0];
    const float* tgt = (const float*)d_in[1];
    const float* W   = (const float*)d_in[2];
    const float* bl  = (const float*)d_in[3];
    const float* wsc = (const float*)d_in[4];
    // d_in[5] (b_score): constant shift under softmax -> unused.
    float* out = (float*)d_out;

    // nz=8 needs (2*524288 + 8*262144 + 262144)*4 = 13,631,488 B of ws.
    const int nz = (ws_size >= 13631488u) ? 8 : 4;
    const int dchunk = 1024 / nz;

    float* A   = (float*)d_ws;                  // 512*1024
    float* B   = A + 524288;                    // 512*1024
    float* P   = B + 524288;                    // nz * 262144
    float* wgt = P + (size_t)nz * 262144;       // 262144
    float* P4  = P;                             // alias: P dead after k3

    k1_gemm_ab<<<dim3(16, 16),     256, 0, stream>>>(rnn, tgt, W, bl, A, B);
    k2_scores <<<dim3(16, 16, nz), 256, 0, stream>>>(A, B, wsc, P, dchunk);
    k3_softmax<<<512,              256, 0, stream>>>(P, wgt, nz);
    k4_out    <<<dim3(16, 16, 4),  256, 0, stream>>>(wgt, rnn, P4);
    k5_reduce <<<256,              256, 0, stream>>>(P4, out);
}

// Round 5
// 95.543 us; speedup vs baseline: 1.5434x; 1.0716x over previous
//
#include <hip/hip_runtime.h>

// Bahdanau additive attention, S=T=512, DU=DT=512, D=1024, fp32.
// score[t,s] = b_s + sum_d w[d]*tanh(A[s,d]+B[t,d]);  out = softmax_s(score) @ rnn
// tanh(x) = 1 - 2/(exp(2x)+1)  ->  score = const - 2*sum_d w*rcp(exp2(C2*(a+b))+1)
// const drops under softmax; C2=2*log2(e) folded into k1 epilogue.
// Split ws layout (floats): A0|A1|B0|B1 (4x512K) | P[8][256K] | wgt[256K] = 17.8 MB
// Fallback (R4) layout: A|B|P[8]|wgt = 13.6 MB, no K-split.

#define C2F 2.8853900817779268f   // 2*log2(e)

__device__ __forceinline__ float2 pk_add(float2 a, float2 b) {
    return make_float2(a.x + b.x, a.y + b.y);
}
__device__ __forceinline__ float2 pk_fma(float2 a, float2 b, float2 c) {
    return make_float2(__builtin_fmaf(a.x, b.x, c.x), __builtin_fmaf(a.y, b.y, c.y));
}

// ---- k1: partial GEMM. i in [0,1024): i<512 -> A (in=rnn), else B (in=tgt, +bias).
// 64x64 tile, 4x4 micro, k-chunk 32, K split ksplit ways via blockIdx.z.
__global__ __launch_bounds__(256, 4) void k1_gemm_ab(
    const float* __restrict__ rnn, const float* __restrict__ tgt,
    const float* __restrict__ W, const float* __restrict__ bl,
    float* __restrict__ Abuf, float* __restrict__ Bbuf, int ksplit)
{
    __shared__ float xt[32][68];   // [k][i]  (stride 68: b128-aligned, low conflict)
    __shared__ float wt[32][68];   // [k][j]
    const int j0 = blockIdx.x * 64;
    const int i0 = blockIdx.y * 64;
    const int kz = blockIdx.z;
    const int klen = 512 / ksplit;
    const int kbase = kz * klen;
    const bool isB = (i0 >= 512);
    const float* __restrict__ in = isB ? tgt : rnn;
    const int irow0 = isB ? (i0 - 512) : i0;
    const int koff = isB ? 512 : 0;
    const int tid = threadIdx.x;
    const int lrow = tid >> 2;     // 0..63
    const int kq   = tid & 3;      // k offset = kq*8
    const int ti   = tid >> 4;     // 0..15 -> i micro base ti*4
    const int tj   = tid & 15;     // 0..15 -> j micro base tj*4
    const float* __restrict__ inp = in + (size_t)(irow0 + lrow) * 512 + kbase + kq * 8;
    const float* __restrict__ wp  = W  + (size_t)(j0 + lrow) * 1024 + koff + kbase + kq * 8;
    float2 acc01[4] = {}, acc23[4] = {};
    float4 x0 = *(const float4*)(inp);
    float4 x1 = *(const float4*)(inp + 4);
    float4 w0 = *(const float4*)(wp);
    float4 w1 = *(const float4*)(wp + 4);
    for (int k0 = 0; k0 < klen; k0 += 32) {
        __syncthreads();
        xt[kq*8+0][lrow] = x0.x; xt[kq*8+1][lrow] = x0.y; xt[kq*8+2][lrow] = x0.z; xt[kq*8+3][lrow] = x0.w;
        xt[kq*8+4][lrow] = x1.x; xt[kq*8+5][lrow] = x1.y; xt[kq*8+6][lrow] = x1.z; xt[kq*8+7][lrow] = x1.w;
        wt[kq*8+0][lrow] = w0.x; wt[kq*8+1][lrow] = w0.y; wt[kq*8+2][lrow] = w0.z; wt[kq*8+3][lrow] = w0.w;
        wt[kq*8+4][lrow] = w1.x; wt[kq*8+5][lrow] = w1.y; wt[kq*8+6][lrow] = w1.z; wt[kq*8+7][lrow] = w1.w;
        __syncthreads();
        if (k0 + 32 < klen) {
            x0 = *(const float4*)(inp + k0 + 32);
            x1 = *(const float4*)(inp + k0 + 36);
            w0 = *(const float4*)(wp + k0 + 32);
            w1 = *(const float4*)(wp + k0 + 36);
        }
        #pragma unroll
        for (int k = 0; k < 32; ++k) {
            const float4 av = *(const float4*)&xt[k][ti * 4];
            const float4 bv = *(const float4*)&wt[k][tj * 4];
            const float2 b01 = make_float2(bv.x, bv.y);
            const float2 b23 = make_float2(bv.z, bv.w);
            const float ar[4] = {av.x, av.y, av.z, av.w};
            #pragma unroll
            for (int r = 0; r < 4; ++r) {
                const float2 a2 = make_float2(ar[r], ar[r]);
                acc01[r] = pk_fma(a2, b01, acc01[r]);
                acc23[r] = pk_fma(a2, b23, acc23[r]);
            }
        }
    }
    float4 bq = make_float4(0.f, 0.f, 0.f, 0.f);
    if (isB && kz == ksplit - 1) bq = *(const float4*)(bl + j0 + tj * 4);
    float* __restrict__ dst = (isB ? Bbuf : Abuf) + (size_t)kz * 524288;
    #pragma unroll
    for (int r = 0; r < 4; ++r) {
        float4 o;
        o.x = (acc01[r].x + bq.x) * C2F;
        o.y = (acc01[r].y + bq.y) * C2F;
        o.z = (acc23[r].x + bq.z) * C2F;
        o.w = (acc23[r].y + bq.w) * C2F;
        *(float4*)(dst + (size_t)(irow0 + ti * 4 + r) * 1024 + j0 + tj * 4) = o;
    }
}

// ---- k1b: A0 += A1; B0 += B1 (only on split path) ----
__global__ __launch_bounds__(256, 4) void k1b_sum(float* __restrict__ ws4)
{
    const int i = (blockIdx.x * 256 + threadIdx.x) * 4;
    float4 a = *(const float4*)(ws4 + i);
    const float4 a1 = *(const float4*)(ws4 + 524288 + i);
    float4 b = *(const float4*)(ws4 + 2 * 524288 + i);
    const float4 b1 = *(const float4*)(ws4 + 3 * 524288 + i);
    a.x += a1.x; a.y += a1.y; a.z += a1.z; a.w += a1.w;
    b.x += b1.x; b.y += b1.y; b.z += b1.z; b.w += b1.w;
    *(float4*)(ws4 + i) = a;
    *(float4*)(ws4 + 2 * 524288 + i) = b;
}

// ---- k2 (hot): P[z][t][s] = sum_{d in chunk z} w[d] * rcp(exp2(a+b)+1) ----
// 32x32 (t,s) tile, 2x2 micro (packed), d split 8 ways; register-prefetch.
__global__ __launch_bounds__(256, 4) void k2_scores(
    const float* __restrict__ A, const float* __restrict__ Bm,
    const float* __restrict__ wsc, float* __restrict__ P, int dchunk)
{
    __shared__ float at[32][34];   // [d][s]
    __shared__ float bt[32][34];   // [d][t]
    __shared__ float wl[256];
    const int s0 = blockIdx.x * 32;
    const int t0 = blockIdx.y * 32;
    const int dz = blockIdx.z * dchunk;
    const int tid = threadIdx.x;
    if (tid < dchunk) wl[tid] = wsc[dz + tid];
    const int lrow = tid >> 3;
    const int q    = tid & 7;
    const int ss   = (tid & 15) * 2;
    const int tt   = (tid >> 4) * 2;
    const float* __restrict__ Arow = A  + (size_t)(s0 + lrow) * 1024 + dz + q * 4;
    const float* __restrict__ Brow = Bm + (size_t)(t0 + lrow) * 1024 + dz + q * 4;
    float2 acc0 = make_float2(0.f, 0.f);   // {P[t][s], P[t][s+1]}
    float2 acc1 = make_float2(0.f, 0.f);   // {P[t+1][s], P[t+1][s+1]}
    const float2 one2 = make_float2(1.f, 1.f);
    float4 av = *(const float4*)(Arow);
    float4 bv = *(const float4*)(Brow);
    for (int d0 = 0; d0 < dchunk; d0 += 32) {
        __syncthreads();
        at[q*4+0][lrow] = av.x; at[q*4+1][lrow] = av.y;
        at[q*4+2][lrow] = av.z; at[q*4+3][lrow] = av.w;
        bt[q*4+0][lrow] = bv.x; bt[q*4+1][lrow] = bv.y;
        bt[q*4+2][lrow] = bv.z; bt[q*4+3][lrow] = bv.w;
        __syncthreads();
        if (d0 + 32 < dchunk) {
            av = *(const float4*)(Arow + d0 + 32);
            bv = *(const float4*)(Brow + d0 + 32);
        }
        #pragma unroll
        for (int d = 0; d < 32; ++d) {
            const float w = wl[d0 + d];
            const float2 w2 = make_float2(w, w);
            const float2 a = *(const float2*)&at[d][ss];
            const float2 b = *(const float2*)&bt[d][tt];
            const float2 x0 = pk_add(a, make_float2(b.x, b.x));
            const float2 x1 = pk_add(a, make_float2(b.y, b.y));
            float2 e0, e1;
            e0.x = __builtin_amdgcn_exp2f(x0.x);
            e0.y = __builtin_amdgcn_exp2f(x0.y);
            e1.x = __builtin_amdgcn_exp2f(x1.x);
            e1.y = __builtin_amdgcn_exp2f(x1.y);
            e0 = pk_add(e0, one2);
            e1 = pk_add(e1, one2);
            float2 r0, r1;
            r0.x = __builtin_amdgcn_rcpf(e0.x);
            r0.y = __builtin_amdgcn_rcpf(e0.y);
            r1.x = __builtin_amdgcn_rcpf(e1.x);
            r1.y = __builtin_amdgcn_rcpf(e1.y);
            acc0 = pk_fma(w2, r0, acc0);
            acc1 = pk_fma(w2, r1, acc1);
        }
    }
    float* __restrict__ Pz = P + (size_t)blockIdx.z * 512 * 512;
    *(float2*)(Pz + (size_t)(t0 + tt) * 512 + s0 + ss)     = acc0;
    *(float2*)(Pz + (size_t)(t0 + tt + 1) * 512 + s0 + ss) = acc1;
}

// ---- k3: weights[t][:] = softmax_s( -2 * sum_z P_z[t][:] ) ----
__global__ __launch_bounds__(256, 4) void k3_softmax(
    const float* __restrict__ P, float* __restrict__ wgt, int nz)
{
    __shared__ float wm[4];
    __shared__ float wsum[4];
    const int t = blockIdx.x;
    const int tid = threadIdx.x;
    const size_t base = (size_t)t * 512 + tid * 2;
    float sx = 0.f, sy = 0.f;
    for (int z = 0; z < nz; ++z) {
        const float2 p = *(const float2*)(P + base + (size_t)z * 262144);
        sx += p.x; sy += p.y;
    }
    const float x0 = -2.f * sx;
    const float x1 = -2.f * sy;
    float m = fmaxf(x0, x1);
    #pragma unroll
    for (int off = 32; off; off >>= 1) m = fmaxf(m, __shfl_xor(m, off));
    if ((tid & 63) == 0) wm[tid >> 6] = m;
    __syncthreads();
    m = fmaxf(fmaxf(wm[0], wm[1]), fmaxf(wm[2], wm[3]));
    const float L2E = 1.4426950408889634f;
    const float e0 = __builtin_amdgcn_exp2f((x0 - m) * L2E);
    const float e1 = __builtin_amdgcn_exp2f((x1 - m) * L2E);
    float s = e0 + e1;
    #pragma unroll
    for (int off = 32; off; off >>= 1) s += __shfl_xor(s, off);
    if ((tid & 63) == 0) wsum[tid >> 6] = s;
    __syncthreads();
    s = wsum[0] + wsum[1] + wsum[2] + wsum[3];
    const float inv = 1.0f / s;
    float2 o; o.x = e0 * inv; o.y = e1 * inv;
    *(float2*)(wgt + (size_t)t * 512 + tid * 2) = o;
}

// ---- k4: P4[z] = wgt[:, z*128:(z+1)*128] @ rnn[z*128:(z+1)*128, :] ----
__global__ __launch_bounds__(256, 4) void k4_out(
    const float* __restrict__ wgt, const float* __restrict__ rnn,
    float* __restrict__ P4)
{
    __shared__ float wt_t[32][36];  // [s][t]
    __shared__ float rn[32][36];    // [s][d]
    const int t0 = blockIdx.y * 32;
    const int d0 = blockIdx.x * 32;
    const int z  = blockIdx.z;
    const int tid = threadIdx.x;
    const int lrow = tid >> 3;
    const int q    = tid & 7;
    const int tt   = (tid >> 4) * 2;
    const int dd   = (tid & 15) * 2;
    float2 acc0 = make_float2(0.f, 0.f);   // {out[t][d], out[t][d+1]}
    float2 acc1 = make_float2(0.f, 0.f);   // {out[t+1][d], out[t+1][d+1]}
    for (int s0 = z * 128; s0 < z * 128 + 128; s0 += 32) {
        const float4 wv = *(const float4*)(wgt + (size_t)(t0 + lrow) * 512 + s0 + q * 4);
        const float4 rv = *(const float4*)(rnn + (size_t)(s0 + lrow) * 512 + d0 + q * 4);
        __syncthreads();
        wt_t[q*4+0][lrow] = wv.x; wt_t[q*4+1][lrow] = wv.y;
        wt_t[q*4+2][lrow] = wv.z; wt_t[q*4+3][lrow] = wv.w;
        rn[lrow][q*4+0] = rv.x; rn[lrow][q*4+1] = rv.y;
        rn[lrow][q*4+2] = rv.z; rn[lrow][q*4+3] = rv.w;
        __syncthreads();
        #pragma unroll
        for (int s = 0; s < 32; ++s) {
            const float2 wv2 = *(const float2*)&wt_t[s][tt];
            const float2 rv2 = *(const float2*)&rn[s][dd];
            acc0 = pk_fma(make_float2(wv2.x, wv2.x), rv2, acc0);
            acc1 = pk_fma(make_float2(wv2.y, wv2.y), rv2, acc1);
        }
    }
    float* __restrict__ Pz = P4 + (size_t)z * 262144;
    *(float2*)(Pz + (size_t)(t0 + tt) * 512 + d0 + dd)     = acc0;
    *(float2*)(Pz + (size_t)(t0 + tt + 1) * 512 + d0 + dd) = acc1;
}

// ---- k5: out = P4[0]+P4[1]+P4[2]+P4[3] ----
__global__ __launch_bounds__(256, 4) void k5_reduce(
    const float* __restrict__ P4, float* __restrict__ out)
{
    const int i = (blockIdx.x * 256 + threadIdx.x) * 4;
    float4 a = *(const float4*)(P4 + i);
    const float4 b = *(const float4*)(P4 + 262144 + i);
    const float4 c = *(const float4*)(P4 + 2 * 262144 + i);
    const float4 d = *(const float4*)(P4 + 3 * 262144 + i);
    a.x += b.x + c.x + d.x;
    a.y += b.y + c.y + d.y;
    a.z += b.z + c.z + d.z;
    a.w += b.w + c.w + d.w;
    *(float4*)(out + i) = a;
}

extern "C" void kernel_launch(void* const* d_in, const int* in_sizes, int n_in,
                              void* d_out, int out_size, void* d_ws, size_t ws_size,
                              hipStream_t stream) {
    const float* rnn = (const float*)d_in[0];
    const float* tgt = (const float*)d_in[1];
    const float* W   = (const float*)d_in[2];
    const float* bl  = (const float*)d_in[3];
    const float* wsc = (const float*)d_in[4];
    // d_in[5] (b_score): constant shift under softmax -> unused.
    float* out = (float*)d_out;

    const int nz = 8;
    const int dchunk = 1024 / nz;
    float* ws = (float*)d_ws;

    // Split path: A0|A1|B0|B1|P[8]|wgt = (4*524288 + 8*262144 + 262144)*4 = 17,825,792 B
    const bool split = (ws_size >= 17825792u);

    if (split) {
        float* A   = ws;                         // A0 (becomes A after k1b)
        float* B   = ws + 2 * 524288;            // B0 (becomes B after k1b)
        float* P   = ws + 4 * 524288;
        float* wgt = P + (size_t)nz * 262144;
        float* P4  = P;                          // alias: P dead after k3
        k1_gemm_ab<<<dim3(16, 16, 2),  256, 0, stream>>>(rnn, tgt, W, bl, A, B, 2);
        k1b_sum   <<<512,              256, 0, stream>>>(ws);
        k2_scores <<<dim3(16, 16, nz), 256, 0, stream>>>(A, B, wsc, P, dchunk);
        k3_softmax<<<512,              256, 0, stream>>>(P, wgt, nz);
        k4_out    <<<dim3(16, 16, 4),  256, 0, stream>>>(wgt, rnn, P4);
        k5_reduce <<<256,              256, 0, stream>>>(P4, out);
    } else {
        // R4-proven fallback: A|B|P[8]|wgt = 13,631,488 B, no K-split.
        float* A   = ws;
        float* B   = ws + 524288;
        float* P   = ws + 2 * 524288;
        float* wgt = P + (size_t)nz * 262144;
        float* P4  = P;
        k1_gemm_ab<<<dim3(16, 16, 1),  256, 0, stream>>>(rnn, tgt, W, bl, A, B, 1);
        k2_scores <<<dim3(16, 16, nz), 256, 0, stream>>>(A, B, wsc, P, dchunk);
        k3_softmax<<<512,              256, 0, stream>>>(P, wgt, nz);
        k4_out    <<<dim3(16, 16, 4),  256, 0, stream>>>(wgt, rnn, P4);
        k5_reduce <<<256,              256, 0, stream>>>(P4, out);
    }
}

// Round 6
// 79.652 us; speedup vs baseline: 1.8514x; 1.1995x over previous
//
#include <hip/hip_runtime.h>

// Bahdanau additive attention, S=T=512, DU=DT=512, D=1024, fp32.
// score[t,s] = b_s + sum_d w[d]*tanh(A[s,d]+B[t,d]);  out = softmax_s(score) @ rnn
// tanh(x) = 1 - 2/(exp(2x)+1); const shift drops under softmax.
// KEY FACTORIZATION: exp2(C2*(a+b)) = EA[s,d]*EB[t,d] with EA=exp2(C2*a), EB=exp2(C2*b)
// precomputed in k1/k1b epilogues -> k2 inner loop has NO exp2, only mul+add+rcp+fma.
// Split ws layout (floats): A0|A1|B0|B1 (4x512K) | P[8][256K] | wgt[256K] = 17.8 MB
// Fallback layout: A|B|P[8]|wgt = 13.6 MB, no K-split.

#define C2F 2.8853900817779268f   // 2*log2(e)

// ---- k1: partial GEMM. i in [0,1024): i<512 -> A (in=rnn), else B (in=tgt, +bias).
// 64x64 tile, 4x4 micro, k-chunk 32, K split ksplit ways via blockIdx.z.
// doexp!=0 (no-split path): epilogue writes exp2(C2*(acc+bias)) directly.
__global__ __launch_bounds__(256, 4) void k1_gemm_ab(
    const float* __restrict__ rnn, const float* __restrict__ tgt,
    const float* __restrict__ W, const float* __restrict__ bl,
    float* __restrict__ Abuf, float* __restrict__ Bbuf, int ksplit, int doexp)
{
    __shared__ float xt[32][68];   // [k][i]
    __shared__ float wt[32][68];   // [k][j]
    const int j0 = blockIdx.x * 64;
    const int i0 = blockIdx.y * 64;
    const int kz = blockIdx.z;
    const int klen = 512 / ksplit;
    const int kbase = kz * klen;
    const bool isB = (i0 >= 512);
    const float* __restrict__ in = isB ? tgt : rnn;
    const int irow0 = isB ? (i0 - 512) : i0;
    const int koff = isB ? 512 : 0;
    const int tid = threadIdx.x;
    const int lrow = tid >> 2;     // 0..63
    const int kq   = tid & 3;      // k offset = kq*8
    const int ti   = tid >> 4;     // 0..15 -> i micro base ti*4
    const int tj   = tid & 15;     // 0..15 -> j micro base tj*4
    const float* __restrict__ inp = in + (size_t)(irow0 + lrow) * 512 + kbase + kq * 8;
    const float* __restrict__ wp  = W  + (size_t)(j0 + lrow) * 1024 + koff + kbase + kq * 8;
    float acc[4][4] = {};
    float4 x0 = *(const float4*)(inp);
    float4 x1 = *(const float4*)(inp + 4);
    float4 w0 = *(const float4*)(wp);
    float4 w1 = *(const float4*)(wp + 4);
    for (int k0 = 0; k0 < klen; k0 += 32) {
        __syncthreads();
        xt[kq*8+0][lrow] = x0.x; xt[kq*8+1][lrow] = x0.y; xt[kq*8+2][lrow] = x0.z; xt[kq*8+3][lrow] = x0.w;
        xt[kq*8+4][lrow] = x1.x; xt[kq*8+5][lrow] = x1.y; xt[kq*8+6][lrow] = x1.z; xt[kq*8+7][lrow] = x1.w;
        wt[kq*8+0][lrow] = w0.x; wt[kq*8+1][lrow] = w0.y; wt[kq*8+2][lrow] = w0.z; wt[kq*8+3][lrow] = w0.w;
        wt[kq*8+4][lrow] = w1.x; wt[kq*8+5][lrow] = w1.y; wt[kq*8+6][lrow] = w1.z; wt[kq*8+7][lrow] = w1.w;
        __syncthreads();
        if (k0 + 32 < klen) {
            x0 = *(const float4*)(inp + k0 + 32);
            x1 = *(const float4*)(inp + k0 + 36);
            w0 = *(const float4*)(wp + k0 + 32);
            w1 = *(const float4*)(wp + k0 + 36);
        }
        #pragma unroll
        for (int k = 0; k < 32; ++k) {
            const float4 av = *(const float4*)&xt[k][ti * 4];
            const float4 bv = *(const float4*)&wt[k][tj * 4];
            const float ar[4] = {av.x, av.y, av.z, av.w};
            const float br[4] = {bv.x, bv.y, bv.z, bv.w};
            #pragma unroll
            for (int r = 0; r < 4; ++r)
                #pragma unroll
                for (int c = 0; c < 4; ++c)
                    acc[r][c] = __builtin_fmaf(ar[r], br[c], acc[r][c]);
        }
    }
    float4 bq = make_float4(0.f, 0.f, 0.f, 0.f);
    if (isB && kz == ksplit - 1) bq = *(const float4*)(bl + j0 + tj * 4);
    float* __restrict__ dst = (isB ? Bbuf : Abuf) + (size_t)kz * 524288;
    #pragma unroll
    for (int r = 0; r < 4; ++r) {
        float4 o;
        o.x = (acc[r][0] + bq.x) * C2F;
        o.y = (acc[r][1] + bq.y) * C2F;
        o.z = (acc[r][2] + bq.z) * C2F;
        o.w = (acc[r][3] + bq.w) * C2F;
        if (doexp) {
            o.x = __builtin_amdgcn_exp2f(o.x);
            o.y = __builtin_amdgcn_exp2f(o.y);
            o.z = __builtin_amdgcn_exp2f(o.z);
            o.w = __builtin_amdgcn_exp2f(o.w);
        }
        *(float4*)(dst + (size_t)(irow0 + ti * 4 + r) * 1024 + j0 + tj * 4) = o;
    }
}

// ---- k1b: A0 = exp2(A0+A1); B0 = exp2(B0+B1) (split path only) ----
__global__ __launch_bounds__(256, 4) void k1b_sum(float* __restrict__ ws4)
{
    const int i = (blockIdx.x * 256 + threadIdx.x) * 4;
    const float4 a0 = *(const float4*)(ws4 + i);
    const float4 a1 = *(const float4*)(ws4 + 524288 + i);
    const float4 b0 = *(const float4*)(ws4 + 2 * 524288 + i);
    const float4 b1 = *(const float4*)(ws4 + 3 * 524288 + i);
    float4 a, b;
    a.x = __builtin_amdgcn_exp2f(a0.x + a1.x);
    a.y = __builtin_amdgcn_exp2f(a0.y + a1.y);
    a.z = __builtin_amdgcn_exp2f(a0.z + a1.z);
    a.w = __builtin_amdgcn_exp2f(a0.w + a1.w);
    b.x = __builtin_amdgcn_exp2f(b0.x + b1.x);
    b.y = __builtin_amdgcn_exp2f(b0.y + b1.y);
    b.z = __builtin_amdgcn_exp2f(b0.z + b1.z);
    b.w = __builtin_amdgcn_exp2f(b0.w + b1.w);
    *(float4*)(ws4 + i) = a;
    *(float4*)(ws4 + 2 * 524288 + i) = b;
}

// ---- k2 (hot): P[z][t][s] = sum_{d in chunk z} w[d] * rcp(EA[s,d]*EB[t,d] + 1) ----
// 32x32 (t,s) tile, 2x2 micro, d split 8 ways; register-prefetch. NO exp2 inside.
__global__ __launch_bounds__(256, 4) void k2_scores(
    const float* __restrict__ EA, const float* __restrict__ EB,
    const float* __restrict__ wsc, float* __restrict__ P, int dchunk)
{
    __shared__ float at[32][34];   // [d][s]
    __shared__ float bt[32][34];   // [d][t]
    __shared__ float wl[256];
    const int s0 = blockIdx.x * 32;
    const int t0 = blockIdx.y * 32;
    const int dz = blockIdx.z * dchunk;
    const int tid = threadIdx.x;
    if (tid < dchunk) wl[tid] = wsc[dz + tid];
    const int lrow = tid >> 3;
    const int q    = tid & 7;
    const int ss   = (tid & 15) * 2;
    const int tt   = (tid >> 4) * 2;
    const float* __restrict__ Arow = EA + (size_t)(s0 + lrow) * 1024 + dz + q * 4;
    const float* __restrict__ Brow = EB + (size_t)(t0 + lrow) * 1024 + dz + q * 4;
    float acc00 = 0.f, acc01 = 0.f, acc10 = 0.f, acc11 = 0.f;
    float4 av = *(const float4*)(Arow);
    float4 bv = *(const float4*)(Brow);
    for (int d0 = 0; d0 < dchunk; d0 += 32) {
        __syncthreads();
        at[q*4+0][lrow] = av.x; at[q*4+1][lrow] = av.y;
        at[q*4+2][lrow] = av.z; at[q*4+3][lrow] = av.w;
        bt[q*4+0][lrow] = bv.x; bt[q*4+1][lrow] = bv.y;
        bt[q*4+2][lrow] = bv.z; bt[q*4+3][lrow] = bv.w;
        __syncthreads();
        if (d0 + 32 < dchunk) {             // prefetch next chunk under compute
            av = *(const float4*)(Arow + d0 + 32);
            bv = *(const float4*)(Brow + d0 + 32);
        }
        #pragma unroll
        for (int d = 0; d < 32; ++d) {
            const float w = wl[d0 + d];
            const float2 a = *(const float2*)&at[d][ss];
            const float2 b = *(const float2*)&bt[d][tt];
            acc00 = __builtin_fmaf(w, __builtin_amdgcn_rcpf(__builtin_fmaf(a.x, b.x, 1.f)), acc00);
            acc01 = __builtin_fmaf(w, __builtin_amdgcn_rcpf(__builtin_fmaf(a.y, b.x, 1.f)), acc01);
            acc10 = __builtin_fmaf(w, __builtin_amdgcn_rcpf(__builtin_fmaf(a.x, b.y, 1.f)), acc10);
            acc11 = __builtin_fmaf(w, __builtin_amdgcn_rcpf(__builtin_fmaf(a.y, b.y, 1.f)), acc11);
        }
    }
    float* __restrict__ Pz = P + (size_t)blockIdx.z * 512 * 512;
    float2 o0, o1;
    o0.x = acc00; o0.y = acc01;
    o1.x = acc10; o1.y = acc11;
    *(float2*)(Pz + (size_t)(t0 + tt) * 512 + s0 + ss)     = o0;
    *(float2*)(Pz + (size_t)(t0 + tt + 1) * 512 + s0 + ss) = o1;
}

// ---- k3: weights[t][:] = softmax_s( -2 * sum_z P_z[t][:] ) ----
__global__ __launch_bounds__(256, 4) void k3_softmax(
    const float* __restrict__ P, float* __restrict__ wgt, int nz)
{
    __shared__ float wm[4];
    __shared__ float wsum[4];
    const int t = blockIdx.x;
    const int tid = threadIdx.x;
    const size_t base = (size_t)t * 512 + tid * 2;
    float sx = 0.f, sy = 0.f;
    for (int z = 0; z < nz; ++z) {
        const float2 p = *(const float2*)(P + base + (size_t)z * 262144);
        sx += p.x; sy += p.y;
    }
    const float x0 = -2.f * sx;
    const float x1 = -2.f * sy;
    float m = fmaxf(x0, x1);
    #pragma unroll
    for (int off = 32; off; off >>= 1) m = fmaxf(m, __shfl_xor(m, off));
    if ((tid & 63) == 0) wm[tid >> 6] = m;
    __syncthreads();
    m = fmaxf(fmaxf(wm[0], wm[1]), fmaxf(wm[2], wm[3]));
    const float L2E = 1.4426950408889634f;
    const float e0 = __builtin_amdgcn_exp2f((x0 - m) * L2E);
    const float e1 = __builtin_amdgcn_exp2f((x1 - m) * L2E);
    float s = e0 + e1;
    #pragma unroll
    for (int off = 32; off; off >>= 1) s += __shfl_xor(s, off);
    if ((tid & 63) == 0) wsum[tid >> 6] = s;
    __syncthreads();
    s = wsum[0] + wsum[1] + wsum[2] + wsum[3];
    const float inv = 1.0f / s;
    float2 o; o.x = e0 * inv; o.y = e1 * inv;
    *(float2*)(wgt + (size_t)t * 512 + tid * 2) = o;
}

// ---- k4: P4[z] = wgt[:, z*128:(z+1)*128] @ rnn[z*128:(z+1)*128, :] ----
__global__ __launch_bounds__(256, 4) void k4_out(
    const float* __restrict__ wgt, const float* __restrict__ rnn,
    float* __restrict__ P4)
{
    __shared__ float wt_t[32][36];  // [s][t]
    __shared__ float rn[32][36];    // [s][d]
    const int t0 = blockIdx.y * 32;
    const int d0 = blockIdx.x * 32;
    const int z  = blockIdx.z;
    const int tid = threadIdx.x;
    const int lrow = tid >> 3;
    const int q    = tid & 7;
    const int tt   = (tid >> 4) * 2;
    const int dd   = (tid & 15) * 2;
    float a00 = 0.f, a01 = 0.f, a10 = 0.f, a11 = 0.f;
    for (int s0 = z * 128; s0 < z * 128 + 128; s0 += 32) {
        const float4 wv = *(const float4*)(wgt + (size_t)(t0 + lrow) * 512 + s0 + q * 4);
        const float4 rv = *(const float4*)(rnn + (size_t)(s0 + lrow) * 512 + d0 + q * 4);
        __syncthreads();
        wt_t[q*4+0][lrow] = wv.x; wt_t[q*4+1][lrow] = wv.y;
        wt_t[q*4+2][lrow] = wv.z; wt_t[q*4+3][lrow] = wv.w;
        rn[lrow][q*4+0] = rv.x; rn[lrow][q*4+1] = rv.y;
        rn[lrow][q*4+2] = rv.z; rn[lrow][q*4+3] = rv.w;
        __syncthreads();
        #pragma unroll
        for (int s = 0; s < 32; ++s) {
            const float w0 = wt_t[s][tt], w1 = wt_t[s][tt + 1];
            const float r0 = rn[s][dd],   r1 = rn[s][dd + 1];
            a00 = __builtin_fmaf(w0, r0, a00);
            a01 = __builtin_fmaf(w0, r1, a01);
            a10 = __builtin_fmaf(w1, r0, a10);
            a11 = __builtin_fmaf(w1, r1, a11);
        }
    }
    float* __restrict__ Pz = P4 + (size_t)z * 262144;
    Pz[(size_t)(t0 + tt) * 512 + d0 + dd]           = a00;
    Pz[(size_t)(t0 + tt) * 512 + d0 + dd + 1]       = a01;
    Pz[(size_t)(t0 + tt + 1) * 512 + d0 + dd]       = a10;
    Pz[(size_t)(t0 + tt + 1) * 512 + d0 + dd + 1]   = a11;
}

// ---- k5: out = P4[0]+P4[1]+P4[2]+P4[3] ----
__global__ __launch_bounds__(256, 4) void k5_reduce(
    const float* __restrict__ P4, float* __restrict__ out)
{
    const int i = (blockIdx.x * 256 + threadIdx.x) * 4;
    float4 a = *(const float4*)(P4 + i);
    const float4 b = *(const float4*)(P4 + 262144 + i);
    const float4 c = *(const float4*)(P4 + 2 * 262144 + i);
    const float4 d = *(const float4*)(P4 + 3 * 262144 + i);
    a.x += b.x + c.x + d.x;
    a.y += b.y + c.y + d.y;
    a.z += b.z + c.z + d.z;
    a.w += b.w + c.w + d.w;
    *(float4*)(out + i) = a;
}

extern "C" void kernel_launch(void* const* d_in, const int* in_sizes, int n_in,
                              void* d_out, int out_size, void* d_ws, size_t ws_size,
                              hipStream_t stream) {
    const float* rnn = (const float*)d_in[0];
    const float* tgt = (const float*)d_in[1];
    const float* W   = (const float*)d_in[2];
    const float* bl  = (const float*)d_in[3];
    const float* wsc = (const float*)d_in[4];
    // d_in[5] (b_score): constant shift under softmax -> unused.
    float* out = (float*)d_out;

    const int nz = 8;
    const int dchunk = 1024 / nz;
    float* ws = (float*)d_ws;

    // Split path: A0|A1|B0|B1|P[8]|wgt = (4*524288 + 8*262144 + 262144)*4 = 17,825,792 B
    const bool split = (ws_size >= 17825792u);

    if (split) {
        float* A   = ws;                         // becomes EA after k1b
        float* B   = ws + 2 * 524288;            // becomes EB after k1b
        float* P   = ws + 4 * 524288;
        float* wgt = P + (size_t)nz * 262144;
        float* P4  = P;                          // alias: P dead after k3
        k1_gemm_ab<<<dim3(16, 16, 2),  256, 0, stream>>>(rnn, tgt, W, bl, A, B, 2, 0);
        k1b_sum   <<<512,              256, 0, stream>>>(ws);
        k2_scores <<<dim3(16, 16, nz), 256, 0, stream>>>(A, B, wsc, P, dchunk);
        k3_softmax<<<512,              256, 0, stream>>>(P, wgt, nz);
        k4_out    <<<dim3(16, 16, 4),  256, 0, stream>>>(wgt, rnn, P4);
        k5_reduce <<<256,              256, 0, stream>>>(P4, out);
    } else {
        // Fallback: A|B|P[8]|wgt = 13,631,488 B, no K-split; k1 applies exp2 itself.
        float* A   = ws;
        float* B   = ws + 524288;
        float* P   = ws + 2 * 524288;
        float* wgt = P + (size_t)nz * 262144;
        float* P4  = P;
        k1_gemm_ab<<<dim3(16, 16, 1),  256, 0, stream>>>(rnn, tgt, W, bl, A, B, 1, 1);
        k2_scores <<<dim3(16, 16, nz), 256, 0, stream>>>(A, B, wsc, P, dchunk);
        k3_softmax<<<512,              256, 0, stream>>>(P, wgt, nz);
        k4_out    <<<dim3(16, 16, 4),  256, 0, stream>>>(wgt, rnn, P4);
        k5_reduce <<<256,              256, 0, stream>>>(P4, out);
    }
}